// Round 1
// baseline (6048.025 us; speedup 1.0000x reference)
//
#include <hip/hip_runtime.h>
#include <cmath>

#define B_ 128
#define T_ 480
#define BT_ 61440

// output layout (fp32 elements)
#define OUT_SPK1 512
#define OUT_SPK2 3932672
#define OUT_SPK3 11796992

__device__ __forceinline__ double softplus_d(double x) {
    return (x > 0.0) ? (x + log1p(exp(-x))) : log1p(exp(x));
}
__device__ __forceinline__ double sigmoid_d(double x) {
    return 1.0 / (1.0 + exp(-x));
}

// ---------------------------------------------------------------------------
// Kernel 1: conv1 (61440x64 @ 64x64) + bn1 -> xbuf (f64). Also zeros zrow.
// ---------------------------------------------------------------------------
__global__ __launch_bounds__(256)
void conv1_bn(const float* __restrict__ x, const float* __restrict__ w1,
              const float* __restrict__ sc, const float* __restrict__ bi,
              const float* __restrict__ mn, const float* __restrict__ vr,
              double* __restrict__ xo, float* __restrict__ zrow)
{
    __shared__ float wl[64 * 64];
    __shared__ float xl[4 * 64];
    int tid = threadIdx.x;
    if (blockIdx.x == 0 && tid < 128) zrow[tid] = 0.0f;   // zero row for conv3 OOB
#pragma unroll
    for (int i = 0; i < 16; i++) wl[tid + 256 * i] = w1[tid + 256 * i];
    int row0 = blockIdx.x * 4;
    xl[tid] = x[(size_t)row0 * 64 + tid];
    __syncthreads();
    int o = tid & 63, r = tid >> 6;
    double acc = 0.0;
#pragma unroll
    for (int w = 0; w < 64; w++)
        acc = fma((double)xl[r * 64 + w], (double)wl[w * 64 + o], acc);
    double y = (acc - (double)mn[o]) * (1.0 / sqrt((double)vr[o] + 1e-5)) * (double)sc[o]
             + (double)bi[o];
    xo[(size_t)(row0 + r) * 64 + o] = y;
}

// ---------------------------------------------------------------------------
// Kernel 2/4: HLIF scan over T per (b,c).
// ---------------------------------------------------------------------------
__global__ void hlif(const double* __restrict__ xin, float* __restrict__ spk,
                     const float* __restrict__ vth_raw, const float* __restrict__ dec_raw,
                     int C)
{
    int idx = blockIdx.x * blockDim.x + threadIdx.x;
    int b = idx / C, c = idx - b * C;
    double vth = softplus_d((double)vth_raw[c]) + 0.5;
    double dec = sigmoid_d((double)dec_raw[c] + 2.0);
    dec = fmin(fmax(dec, 0.0), 0.99);
    const double* xp = xin + (size_t)b * T_ * C + c;
    float* sp = spk + (size_t)b * T_ * C + c;
    double v = 0.0;
    for (int t = 0; t < T_; t += 8) {
        double xv[8];
#pragma unroll
        for (int u = 0; u < 8; u++) xv[u] = xp[(size_t)(t + u) * C];
#pragma unroll
        for (int u = 0; u < 8; u++) {
            v = v * dec + xv[u];
            double s = (v - vth > 0.0) ? 1.0 : 0.0;
            v -= s * vth;
            sp[(size_t)(t + u) * C] = (float)s;
        }
    }
}

// ---------------------------------------------------------------------------
// Kernel 3: conv2 (K=32, dil=4, pad 62, Cin=64, Cout=128) + bn2 -> xbuf (f64)
// Block: 256 thr = o(128) x th(2); each thread 8 t's. TT=16. Spikes in LDS.
// ---------------------------------------------------------------------------
__global__ __launch_bounds__(256)
void conv2_bn(const float* __restrict__ spk1, const float* __restrict__ w2,
              const float* __restrict__ sc, const float* __restrict__ bi,
              const float* __restrict__ mn, const float* __restrict__ vr,
              double* __restrict__ xo)
{
    __shared__ float S[140 * 64];   // rows t0-62 .. t0+15+62
    int tid = threadIdx.x;
    int bb = blockIdx.x / 30;
    int tt = blockIdx.x - bb * 30;
    int t0 = tt * 16;
    const float* sb = spk1 + (size_t)bb * T_ * 64;
    for (int i = tid; i < 140 * 64; i += 256) {
        int rr = i >> 6, cc = i & 63;
        int t = t0 - 62 + rr;
        S[i] = (t >= 0 && t < T_) ? sb[(size_t)t * 64 + cc] : 0.0f;
    }
    __syncthreads();
    int o = tid & 127, th = tid >> 7;
    double acc[8];
#pragma unroll
    for (int j = 0; j < 8; j++) acc[j] = 0.0;

    for (int k = 0; k < 32; k++) {
        int rbase = th * 8 + 4 * k;   // row for (j) = rbase + j
        for (int cc = 0; cc < 64; cc += 4) {
            float4 sv[8];
#pragma unroll
            for (int j = 0; j < 8; j++)
                sv[j] = *(const float4*)&S[(rbase + j) * 64 + cc];
#pragma unroll
            for (int q = 0; q < 4; q++) {
                double w = (double)w2[(size_t)(k * 64 + cc + q) * 128 + o];
#pragma unroll
                for (int j = 0; j < 8; j++) {
                    float fv = ((const float*)&sv[j])[q];
                    acc[j] = fma(w, (double)fv, acc[j]);
                }
            }
        }
    }
    double m = (double)mn[o], rs = 1.0 / sqrt((double)vr[o] + 1e-5);
    double s_ = (double)sc[o], b_ = (double)bi[o];
    double* xop = xo + ((size_t)bb * T_ + t0 + th * 8) * 128 + o;
#pragma unroll
    for (int j = 0; j < 8; j++) xop[(size_t)j * 128] = (acc[j] - m) * rs * s_ + b_;
}

// ---------------------------------------------------------------------------
// Kernel 5: conv3 (K=32, dil=12, pad 186, Cin=128, Cout=128) + bn3 -> xbuf
// Spikes read from global (L2-resident per b); OOB rows -> zrow.
// ---------------------------------------------------------------------------
__global__ __launch_bounds__(256)
void conv3_bn(const float* __restrict__ spk2, const float* __restrict__ w3,
              const float* __restrict__ sc, const float* __restrict__ bi,
              const float* __restrict__ mn, const float* __restrict__ vr,
              const float* __restrict__ zrow, double* __restrict__ xo)
{
    int tid = threadIdx.x;
    int bb = blockIdx.x / 30;
    int tt = blockIdx.x - bb * 30;
    int t0 = tt * 16;
    const float* sb = spk2 + (size_t)bb * T_ * 128;
    int o = tid & 127, th = tid >> 7;
    double acc[8];
#pragma unroll
    for (int j = 0; j < 8; j++) acc[j] = 0.0;

    for (int k = 0; k < 32; k++) {
        int tb = t0 + th * 8 + 12 * k - 186;
        const float* rp[8];
#pragma unroll
        for (int j = 0; j < 8; j++) {
            int t = tb + j;
            rp[j] = (t >= 0 && t < T_) ? (sb + (size_t)t * 128) : zrow;
        }
        for (int cc = 0; cc < 128; cc += 4) {
            float4 sv[8];
#pragma unroll
            for (int j = 0; j < 8; j++)
                sv[j] = *(const float4*)(rp[j] + cc);
#pragma unroll
            for (int q = 0; q < 4; q++) {
                double w = (double)w3[(size_t)(k * 128 + cc + q) * 128 + o];
#pragma unroll
                for (int j = 0; j < 8; j++) {
                    float fv = ((const float*)&sv[j])[q];
                    acc[j] = fma(w, (double)fv, acc[j]);
                }
            }
        }
    }
    double m = (double)mn[o], rs = 1.0 / sqrt((double)vr[o] + 1e-5);
    double s_ = (double)sc[o], b_ = (double)bi[o];
    double* xop = xo + ((size_t)bb * T_ + t0 + th * 8) * 128 + o;
#pragma unroll
    for (int j = 0; j < 8; j++) xop[(size_t)j * 128] = (acc[j] - m) * rs * s_ + b_;
}

// ---------------------------------------------------------------------------
// Kernel 6: ALIF scan per (b,c), C=128.
// ---------------------------------------------------------------------------
__global__ void alif(const double* __restrict__ xin, float* __restrict__ spk)
{
    int idx = blockIdx.x * blockDim.x + threadIdx.x;
    int b = idx >> 7, c = idx & 127;
    const double* xp = xin + (size_t)b * T_ * 128 + c;
    float* sp = spk + (size_t)b * T_ * 128 + c;
    double v = 0.0, th = 0.0, ps = 0.0;
    const double dd = 0.9, adp = 0.9, beta = 1.8;
    for (int t = 0; t < T_; t += 8) {
        double xv[8];
#pragma unroll
        for (int u = 0; u < 8; u++) xv[u] = xp[(size_t)(t + u) * 128];
#pragma unroll
        for (int u = 0; u < 8; u++) {
            th = th * adp + ps * beta;
            v = v * dd + xv[u];
            double vth = 0.5 + th;
            double s = (v - vth > 0.0) ? 1.0 : 0.0;
            v -= s * vth;
            ps = s;
            sp[(size_t)(t + u) * 128] = (float)s;
        }
    }
}

// ---------------------------------------------------------------------------
// Kernel 7: readout — dense + LI scan + dp + attention + logits. 1 block per b.
// ---------------------------------------------------------------------------
__global__ __launch_bounds__(256)
void readout(const float* __restrict__ spk3, const float* __restrict__ dw,
             const float* __restrict__ db, const float* __restrict__ a1w,
             const float* __restrict__ a1b, const float* __restrict__ a2w,
             const float* __restrict__ a2b, float* __restrict__ out)
{
    __shared__ double dl[480 * 4];
    __shared__ double dp[20 * 4];
    __shared__ double zl[20];
    __shared__ double red[1];
    int b = blockIdx.x, tid = threadIdx.x;
    const float* sp = spk3 + (size_t)b * T_ * 128;

    // dense: (480,128) @ (128,4) + bias
    for (int i = tid; i < 1920; i += 256) {
        int t = i >> 2, j = i & 3;
        const float* row = sp + (size_t)t * 128;
        double acc = 0.0;
        for (int c = 0; c < 128; c++)
            acc = fma((double)row[c], (double)dw[c * 4 + j], acc);
        dl[i] = acc + (double)db[j];
    }
    __syncthreads();
    // LI scan: v = v*0.9 + x*(1-0.9)
    if (tid < 4) {
        const double dec = 0.9, om = 1.0 - 0.9;
        double v = 0.0;
        for (int t = 0; t < T_; t++) {
            v = v * dec + dl[t * 4 + tid] * om;
            dl[t * 4 + tid] = v;
        }
    }
    __syncthreads();
    // dp = mean(last 12) - mean(first 12) per (g, j)
    if (tid < 80) {
        int g = tid >> 2, j = tid & 3;
        double s1 = 0.0, s2 = 0.0;
        for (int u = 0; u < 12; u++) {
            s1 += dl[(g * 24 + u) * 4 + j];
            s2 += dl[(g * 24 + 12 + u) * 4 + j];
        }
        dp[g * 4 + j] = s2 / 12.0 - s1 / 12.0;
    }
    __syncthreads();
    // z[g] = relu(dp@a1w + a1b) @ a2w + a2b
    if (tid < 20) {
        int g = tid;
        double z = (double)a2b[0];
        for (int i = 0; i < 8; i++) {
            double h = (double)a1b[i];
            for (int j = 0; j < 4; j++)
                h = fma(dp[g * 4 + j], (double)a1w[j * 8 + i], h);
            h = fmax(h, 0.0);
            z = fma(h, (double)a2w[i], z);
        }
        zl[g] = z;
    }
    __syncthreads();
    if (tid == 0) {
        double m = zl[0];
        for (int g = 1; g < 20; g++) m = fmax(m, zl[g]);
        double s = 0.0;
        for (int g = 0; g < 20; g++) { zl[g] = exp(zl[g] - m); s += zl[g]; }
        red[0] = s;
    }
    __syncthreads();
    if (tid < 4) {
        double s = red[0];
        double acc = 0.0;
        for (int g = 0; g < 20; g++) acc += dp[g * 4 + tid] * (zl[g] / s);
        out[b * 4 + tid] = (float)acc;
    }
}

// ---------------------------------------------------------------------------
extern "C" void kernel_launch(void* const* d_in, const int* in_sizes, int n_in,
                              void* d_out, int out_size, void* d_ws, size_t ws_size,
                              hipStream_t stream)
{
    const float* x     = (const float*)d_in[0];
    const float* w1    = (const float*)d_in[1];
    const float* bn1s  = (const float*)d_in[2];
    const float* bn1b  = (const float*)d_in[3];
    const float* bn1m  = (const float*)d_in[4];
    const float* bn1v  = (const float*)d_in[5];
    const float* vth1  = (const float*)d_in[6];
    const float* dec1  = (const float*)d_in[7];
    const float* w2    = (const float*)d_in[8];
    const float* bn2s  = (const float*)d_in[9];
    const float* bn2b  = (const float*)d_in[10];
    const float* bn2m  = (const float*)d_in[11];
    const float* bn2v  = (const float*)d_in[12];
    const float* vth2  = (const float*)d_in[13];
    const float* dec2  = (const float*)d_in[14];
    const float* w3    = (const float*)d_in[15];
    const float* bn3s  = (const float*)d_in[16];
    const float* bn3b  = (const float*)d_in[17];
    const float* bn3m  = (const float*)d_in[18];
    const float* bn3v  = (const float*)d_in[19];
    const float* dw    = (const float*)d_in[20];
    const float* db    = (const float*)d_in[21];
    const float* a1w   = (const float*)d_in[22];
    const float* a1b   = (const float*)d_in[23];
    const float* a2w   = (const float*)d_in[24];
    const float* a2b   = (const float*)d_in[25];

    float* out = (float*)d_out;
    double* xbuf = (double*)d_ws;                         // 61440*128 doubles = 62.9 MB
    float* zrow = (float*)(xbuf + (size_t)BT_ * 128);     // 128 zero floats for conv3 OOB

    // Stage 1
    conv1_bn<<<BT_ / 4, 256, 0, stream>>>(x, w1, bn1s, bn1b, bn1m, bn1v, xbuf, zrow);
    hlif<<<(B_ * 64) / 256, 256, 0, stream>>>(xbuf, out + OUT_SPK1, vth1, dec1, 64);
    // Stage 2
    conv2_bn<<<B_ * 30, 256, 0, stream>>>(out + OUT_SPK1, w2, bn2s, bn2b, bn2m, bn2v, xbuf);
    hlif<<<(B_ * 128) / 256, 256, 0, stream>>>(xbuf, out + OUT_SPK2, vth2, dec2, 128);
    // Stage 3
    conv3_bn<<<B_ * 30, 256, 0, stream>>>(out + OUT_SPK2, w3, bn3s, bn3b, bn3m, bn3v, zrow, xbuf);
    alif<<<(B_ * 128) / 256, 256, 0, stream>>>(xbuf, out + OUT_SPK3);
    // Readout
    readout<<<B_, 256, 0, stream>>>(out + OUT_SPK3, dw, db, a1w, a1b, a2w, a2b, out);
}

// Round 3
// 4645.145 us; speedup vs baseline: 1.3020x; 1.3020x over previous
//
#include <hip/hip_runtime.h>
#include <cmath>

#define B_ 128
#define T_ 480
#define BT_ 61440

// output layout (fp32 elements)
#define OUT_SPK1 512
#define OUT_SPK2 3932672
#define OUT_SPK3 11796992

__device__ __forceinline__ double softplus_d(double x) {
    return (x > 0.0) ? (x + log1p(exp(-x))) : log1p(exp(x));
}
__device__ __forceinline__ double sigmoid_d(double x) {
    return 1.0 / (1.0 + exp(-x));
}

// ---------------------------------------------------------------------------
// Kernel 1: conv1 (61440x64 @ 64x64) + bn1 -> xbuf (f64). Also zeros zrow.
// f64 kept here: it's cheap (one dispatch ~ small) and stage-1 margins matter.
// ---------------------------------------------------------------------------
__global__ __launch_bounds__(256)
void conv1_bn(const float* __restrict__ x, const float* __restrict__ w1,
              const float* __restrict__ sc, const float* __restrict__ bi,
              const float* __restrict__ mn, const float* __restrict__ vr,
              double* __restrict__ xo, float* __restrict__ zrow)
{
    __shared__ float wl[64 * 64];
    __shared__ float xl[4 * 64];
    int tid = threadIdx.x;
    if (blockIdx.x == 0 && tid < 128) zrow[tid] = 0.0f;   // zero row for conv3 OOB
#pragma unroll
    for (int i = 0; i < 16; i++) wl[tid + 256 * i] = w1[tid + 256 * i];
    int row0 = blockIdx.x * 4;
    xl[tid] = x[(size_t)row0 * 64 + tid];
    __syncthreads();
    int o = tid & 63, r = tid >> 6;
    double acc = 0.0;
#pragma unroll
    for (int w = 0; w < 64; w++)
        acc = fma((double)xl[r * 64 + w], (double)wl[w * 64 + o], acc);
    double y = (acc - (double)mn[o]) * (1.0 / sqrt((double)vr[o] + 1e-5)) * (double)sc[o]
             + (double)bi[o];
    xo[(size_t)(row0 + r) * 64 + o] = y;
}

// ---------------------------------------------------------------------------
// Kernel 2/4: HLIF scan over T per (b,c).
// ---------------------------------------------------------------------------
__global__ void hlif(const double* __restrict__ xin, float* __restrict__ spk,
                     const float* __restrict__ vth_raw, const float* __restrict__ dec_raw,
                     int C)
{
    int idx = blockIdx.x * blockDim.x + threadIdx.x;
    int b = idx / C, c = idx - b * C;
    double vth = softplus_d((double)vth_raw[c]) + 0.5;
    double dec = sigmoid_d((double)dec_raw[c] + 2.0);
    dec = fmin(fmax(dec, 0.0), 0.99);
    const double* xp = xin + (size_t)b * T_ * C + c;
    float* sp = spk + (size_t)b * T_ * C + c;
    double v = 0.0;
    for (int t = 0; t < T_; t += 8) {
        double xv[8];
#pragma unroll
        for (int u = 0; u < 8; u++) xv[u] = xp[(size_t)(t + u) * C];
#pragma unroll
        for (int u = 0; u < 8; u++) {
            v = v * dec + xv[u];
            double s = (v - vth > 0.0) ? 1.0 : 0.0;
            v -= s * vth;
            sp[(size_t)(t + u) * C] = (float)s;
        }
    }
}

// ---------------------------------------------------------------------------
// Kernel 3: conv2 (K=32, dil=4, pad 62, Cin=64, Cout=128) + bn2 -> xbuf (f64)
// Hybrid precision: per-k 64-term partial in f32 (fmac, no cvt), k-sum in f64.
// ---------------------------------------------------------------------------
__global__ __launch_bounds__(256)
void conv2_bn(const float* __restrict__ spk1, const float* __restrict__ w2,
              const float* __restrict__ sc, const float* __restrict__ bi,
              const float* __restrict__ mn, const float* __restrict__ vr,
              double* __restrict__ xo)
{
    __shared__ float S[140 * 64];   // rows t0-62 .. t0+15+62
    int tid = threadIdx.x;
    int bb = blockIdx.x / 30;
    int tt = blockIdx.x - bb * 30;
    int t0 = tt * 16;
    const float* sb = spk1 + (size_t)bb * T_ * 64;
    for (int i = tid; i < 140 * 64; i += 256) {
        int rr = i >> 6, cc = i & 63;
        int t = t0 - 62 + rr;
        S[i] = (t >= 0 && t < T_) ? sb[(size_t)t * 64 + cc] : 0.0f;
    }
    __syncthreads();
    int o = tid & 127, th = tid >> 7;
    double acc[8];
#pragma unroll
    for (int j = 0; j < 8; j++) acc[j] = 0.0;

    for (int k = 0; k < 32; k++) {
        int rbase = th * 8 + 4 * k;   // row for (j) = rbase + j
        const float* wp = w2 + (size_t)k * 64 * 128 + o;
        float p[8];
#pragma unroll
        for (int j = 0; j < 8; j++) p[j] = 0.0f;
        for (int cc = 0; cc < 64; cc += 4) {
            float4 sv[8];
#pragma unroll
            for (int j = 0; j < 8; j++)
                sv[j] = *(const float4*)&S[(rbase + j) * 64 + cc];
#pragma unroll
            for (int q = 0; q < 4; q++) {
                float w = wp[(size_t)(cc + q) * 128];
#pragma unroll
                for (int j = 0; j < 8; j++)
                    p[j] = fmaf(((const float*)&sv[j])[q], w, p[j]);
            }
        }
#pragma unroll
        for (int j = 0; j < 8; j++) acc[j] += (double)p[j];
    }
    double m = (double)mn[o], rs = 1.0 / sqrt((double)vr[o] + 1e-5);
    double s_ = (double)sc[o], b_ = (double)bi[o];
    double* xop = xo + ((size_t)bb * T_ + t0 + th * 8) * 128 + o;
#pragma unroll
    for (int j = 0; j < 8; j++) xop[(size_t)j * 128] = (acc[j] - m) * rs * s_ + b_;
}

// ---------------------------------------------------------------------------
// Kernel 5: conv3 (K=32, dil=12, pad 186, Cin=128, Cout=128) + bn3 -> xbuf
// Hybrid precision: per-k 128-term partial in f32, k-sum in f64.
// ---------------------------------------------------------------------------
__global__ __launch_bounds__(256)
void conv3_bn(const float* __restrict__ spk2, const float* __restrict__ w3,
              const float* __restrict__ sc, const float* __restrict__ bi,
              const float* __restrict__ mn, const float* __restrict__ vr,
              const float* __restrict__ zrow, double* __restrict__ xo)
{
    int tid = threadIdx.x;
    int bb = blockIdx.x / 30;
    int tt = blockIdx.x - bb * 30;
    int t0 = tt * 16;
    const float* sb = spk2 + (size_t)bb * T_ * 128;
    int o = tid & 127, th = tid >> 7;
    double acc[8];
#pragma unroll
    for (int j = 0; j < 8; j++) acc[j] = 0.0;

    for (int k = 0; k < 32; k++) {
        int tb = t0 + th * 8 + 12 * k - 186;
        const float* rp[8];
#pragma unroll
        for (int j = 0; j < 8; j++) {
            int t = tb + j;
            rp[j] = (t >= 0 && t < T_) ? (sb + (size_t)t * 128) : zrow;
        }
        const float* wp = w3 + (size_t)k * 128 * 128 + o;
        float p[8];
#pragma unroll
        for (int j = 0; j < 8; j++) p[j] = 0.0f;
        for (int cc = 0; cc < 128; cc += 4) {
            float4 sv[8];
#pragma unroll
            for (int j = 0; j < 8; j++)
                sv[j] = *(const float4*)(rp[j] + cc);
#pragma unroll
            for (int q = 0; q < 4; q++) {
                float w = wp[(size_t)(cc + q) * 128];
#pragma unroll
                for (int j = 0; j < 8; j++)
                    p[j] = fmaf(((const float*)&sv[j])[q], w, p[j]);
            }
        }
#pragma unroll
        for (int j = 0; j < 8; j++) acc[j] += (double)p[j];
    }
    double m = (double)mn[o], rs = 1.0 / sqrt((double)vr[o] + 1e-5);
    double s_ = (double)sc[o], b_ = (double)bi[o];
    double* xop = xo + ((size_t)bb * T_ + t0 + th * 8) * 128 + o;
#pragma unroll
    for (int j = 0; j < 8; j++) xop[(size_t)j * 128] = (acc[j] - m) * rs * s_ + b_;
}

// ---------------------------------------------------------------------------
// Kernel 6: ALIF scan per (b,c), C=128.
// ---------------------------------------------------------------------------
__global__ void alif(const double* __restrict__ xin, float* __restrict__ spk)
{
    int idx = blockIdx.x * blockDim.x + threadIdx.x;
    int b = idx >> 7, c = idx & 127;
    const double* xp = xin + (size_t)b * T_ * 128 + c;
    float* sp = spk + (size_t)b * T_ * 128 + c;
    double v = 0.0, th = 0.0, ps = 0.0;
    const double dd = 0.9, adp = 0.9, beta = 1.8;
    for (int t = 0; t < T_; t += 8) {
        double xv[8];
#pragma unroll
        for (int u = 0; u < 8; u++) xv[u] = xp[(size_t)(t + u) * 128];
#pragma unroll
        for (int u = 0; u < 8; u++) {
            th = th * adp + ps * beta;
            v = v * dd + xv[u];
            double vth = 0.5 + th;
            double s = (v - vth > 0.0) ? 1.0 : 0.0;
            v -= s * vth;
            ps = s;
            sp[(size_t)(t + u) * 128] = (float)s;
        }
    }
}

// ---------------------------------------------------------------------------
// Kernel 7: readout — dense + LI scan + dp + attention + logits. 1 block per b.
// ---------------------------------------------------------------------------
__global__ __launch_bounds__(256)
void readout(const float* __restrict__ spk3, const float* __restrict__ dw,
             const float* __restrict__ db, const float* __restrict__ a1w,
             const float* __restrict__ a1b, const float* __restrict__ a2w,
             const float* __restrict__ a2b, float* __restrict__ out)
{
    __shared__ double dl[480 * 4];
    __shared__ double dp[20 * 4];
    __shared__ double zl[20];
    __shared__ double red[1];
    int b = blockIdx.x, tid = threadIdx.x;
    const float* sp = spk3 + (size_t)b * T_ * 128;

    // dense: (480,128) @ (128,4) + bias
    for (int i = tid; i < 1920; i += 256) {
        int t = i >> 2, j = i & 3;
        const float* row = sp + (size_t)t * 128;
        double acc = 0.0;
        for (int c = 0; c < 128; c++)
            acc = fma((double)row[c], (double)dw[c * 4 + j], acc);
        dl[i] = acc + (double)db[j];
    }
    __syncthreads();
    // LI scan: v = v*0.9 + x*(1-0.9)
    if (tid < 4) {
        const double dec = 0.9, om = 1.0 - 0.9;
        double v = 0.0;
        for (int t = 0; t < T_; t++) {
            v = v * dec + dl[t * 4 + tid] * om;
            dl[t * 4 + tid] = v;
        }
    }
    __syncthreads();
    // dp = mean(last 12) - mean(first 12) per (g, j)
    if (tid < 80) {
        int g = tid >> 2, j = tid & 3;
        double s1 = 0.0, s2 = 0.0;
        for (int u = 0; u < 12; u++) {
            s1 += dl[(g * 24 + u) * 4 + j];
            s2 += dl[(g * 24 + 12 + u) * 4 + j];
        }
        dp[g * 4 + j] = s2 / 12.0 - s1 / 12.0;
    }
    __syncthreads();
    // z[g] = relu(dp@a1w + a1b) @ a2w + a2b
    if (tid < 20) {
        int g = tid;
        double z = (double)a2b[0];
        for (int i = 0; i < 8; i++) {
            double h = (double)a1b[i];
            for (int j = 0; j < 4; j++)
                h = fma(dp[g * 4 + j], (double)a1w[j * 8 + i], h);
            h = fmax(h, 0.0);
            z = fma(h, (double)a2w[i], z);
        }
        zl[g] = z;
    }
    __syncthreads();
    if (tid == 0) {
        double m = zl[0];
        for (int g = 1; g < 20; g++) m = fmax(m, zl[g]);
        double s = 0.0;
        for (int g = 0; g < 20; g++) { zl[g] = exp(zl[g] - m); s += zl[g]; }
        red[0] = s;
    }
    __syncthreads();
    if (tid < 4) {
        double s = red[0];
        double acc = 0.0;
        for (int g = 0; g < 20; g++) acc += dp[g * 4 + tid] * (zl[g] / s);
        out[b * 4 + tid] = (float)acc;
    }
}

// ---------------------------------------------------------------------------
extern "C" void kernel_launch(void* const* d_in, const int* in_sizes, int n_in,
                              void* d_out, int out_size, void* d_ws, size_t ws_size,
                              hipStream_t stream)
{
    const float* x     = (const float*)d_in[0];
    const float* w1    = (const float*)d_in[1];
    const float* bn1s  = (const float*)d_in[2];
    const float* bn1b  = (const float*)d_in[3];
    const float* bn1m  = (const float*)d_in[4];
    const float* bn1v  = (const float*)d_in[5];
    const float* vth1  = (const float*)d_in[6];
    const float* dec1  = (const float*)d_in[7];
    const float* w2    = (const float*)d_in[8];
    const float* bn2s  = (const float*)d_in[9];
    const float* bn2b  = (const float*)d_in[10];
    const float* bn2m  = (const float*)d_in[11];
    const float* bn2v  = (const float*)d_in[12];
    const float* vth2  = (const float*)d_in[13];
    const float* dec2  = (const float*)d_in[14];
    const float* w3    = (const float*)d_in[15];
    const float* bn3s  = (const float*)d_in[16];
    const float* bn3b  = (const float*)d_in[17];
    const float* bn3m  = (const float*)d_in[18];
    const float* bn3v  = (const float*)d_in[19];
    const float* dw    = (const float*)d_in[20];
    const float* db    = (const float*)d_in[21];
    const float* a1w   = (const float*)d_in[22];
    const float* a1b   = (const float*)d_in[23];
    const float* a2w   = (const float*)d_in[24];
    const float* a2b   = (const float*)d_in[25];

    float* out = (float*)d_out;
    double* xbuf = (double*)d_ws;                         // 61440*128 doubles = 62.9 MB
    float* zrow = (float*)(xbuf + (size_t)BT_ * 128);     // 128 zero floats for conv3 OOB

    // Stage 1
    conv1_bn<<<BT_ / 4, 256, 0, stream>>>(x, w1, bn1s, bn1b, bn1m, bn1v, xbuf, zrow);
    hlif<<<(B_ * 64) / 256, 256, 0, stream>>>(xbuf, out + OUT_SPK1, vth1, dec1, 64);
    // Stage 2
    conv2_bn<<<B_ * 30, 256, 0, stream>>>(out + OUT_SPK1, w2, bn2s, bn2b, bn2m, bn2v, xbuf);
    hlif<<<(B_ * 128) / 256, 256, 0, stream>>>(xbuf, out + OUT_SPK2, vth2, dec2, 128);
    // Stage 3
    conv3_bn<<<B_ * 30, 256, 0, stream>>>(out + OUT_SPK2, w3, bn3s, bn3b, bn3m, bn3v, zrow, xbuf);
    alif<<<(B_ * 128) / 256, 256, 0, stream>>>(xbuf, out + OUT_SPK3);
    // Readout
    readout<<<B_, 256, 0, stream>>>(out + OUT_SPK3, dw, db, a1w, a1b, a2w, a2b, out);
}